// Round 12
// baseline (125.938 us; speedup 1.0000x reference)
//
#include <hip/hip_runtime.h>
#include <hip/hip_bf16.h>
#include <math.h>

#define N 8192
#define D 256
#define MARGIN 1.0f

#define BM 128
#define BN 128
#define NCH 4            // K-chunks of 64 fp16 elems (128B per row)
#define NB (N / BM)      // 64
#define NTRI (NB * (NB + 1) / 2)   // 2080
#define BCAP 64          // class bucket capacity

#define KINIT 0xFFFFFFFFu
#define QMAXF 524287.0f          // 2^19 - 1
#define IDXMASK 0x1FFFu          // 13 bits (N=8192)

typedef __attribute__((ext_vector_type(8))) _Float16 half8;
typedef __attribute__((ext_vector_type(4))) _Float16 half4;
typedef __attribute__((ext_vector_type(4))) float f32x4;
typedef unsigned int uint32;
typedef unsigned long long u64;

__device__ __forceinline__ uint32 minu(uint32 a, uint32 b) { return a < b ? a : b; }

// ---------------------------------------------------------------------------
// k_conv: f32 -> fp16 plane + class buckets.
// ---------------------------------------------------------------------------
__global__ __launch_bounds__(256) void k_conv(const float* __restrict__ x,
                                              const int* __restrict__ labels,
                                              _Float16* __restrict__ hp,
                                              int* __restrict__ cnt,
                                              int* __restrict__ bkt) {
    int i = blockIdx.x * 256 + threadIdx.x;
    float4 v = reinterpret_cast<const float4*>(x)[i];
    half4 h;
    h[0] = (_Float16)v.x; h[1] = (_Float16)v.y;
    h[2] = (_Float16)v.z; h[3] = (_Float16)v.w;
    reinterpret_cast<half4*>(hp)[i] = h;
    if (i < N) {
        int lb = labels[i];
        int p = atomicAdd(&cnt[lb], 1);
        if (p < BCAP) bkt[lb * BCAP + p] = i;
    }
}

// ---------------------------------------------------------------------------
// k_dpos: one wave per anchor; exact f32 d_pos via class buckets.
// ---------------------------------------------------------------------------
__global__ __launch_bounds__(256) void k_dpos(const float* __restrict__ x,
                                              const int* __restrict__ labels,
                                              const int* __restrict__ cnt,
                                              const int* __restrict__ bkt,
                                              float* __restrict__ sq,
                                              float* __restrict__ dpos) {
    int wave = (blockIdx.x * blockDim.x + threadIdx.x) >> 6;
    int lane = threadIdx.x & 63;
    if (wave >= N) return;
    const int i = wave;

    float4 xi = reinterpret_cast<const float4*>(x + (size_t)i * D)[lane];
    float sqi = xi.x * xi.x + xi.y * xi.y + xi.z * xi.z + xi.w * xi.w;
    for (int m = 32; m >= 1; m >>= 1) sqi += __shfl_xor(sqi, m, 64);

    const int L = labels[i];
    int c = cnt[L]; if (c > BCAP) c = BCAP;
    float dp = -1.0f;

    for (int e = 0; e < c; ++e) {
        int j = bkt[L * BCAP + e];
        if (j == i) continue;
        float4 xj = reinterpret_cast<const float4*>(x + (size_t)j * D)[lane];
        float dotp = xi.x * xj.x + xi.y * xj.y + xi.z * xj.z + xi.w * xj.w;
        float sqjp = xj.x * xj.x + xj.y * xj.y + xj.z * xj.z + xj.w * xj.w;
        for (int m = 32; m >= 1; m >>= 1) {
            dotp += __shfl_xor(dotp, m, 64);
            sqjp += __shfl_xor(sqjp, m, 64);
        }
        float sqd = fmaxf(sqi + sqjp - 2.0f * dotp, 0.0f);
        float dist = sqd > 0.0f ? sqrtf(sqd) : 0.0f;
        dp = fmaxf(dp, dist);
    }

    if (lane == 0) {
        sq[i] = sqi;
        dpos[i] = dp;
    }
}

// ---------------------------------------------------------------------------
// k_main: symmetric fp16 MFMA GEMM, 8 waves (2x4), 64x32/wave, acc + accT
// (both orientations from the same register fragments). r12: epilogue fully
// register-hoisted (labels/thresholds/indices preloaded; zero LDS reads in
// the visit loops), simplified quantization q=clamp(fma(a,-2^18,2^18)),
// hoisted staging addresses. Partial min keys stored with plain stores.
// ---------------------------------------------------------------------------
__global__ __launch_bounds__(512) void k_main(const _Float16* __restrict__ hp,
                                              const int* __restrict__ labels,
                                              const float* __restrict__ dpos,
                                              uint32* __restrict__ pr_n,
                                              uint32* __restrict__ pr_s,
                                              uint32* __restrict__ pc_n,
                                              uint32* __restrict__ pc_s) {
    __shared__ char Abuf[2][BM * 128];   // 16 KB each
    __shared__ char Bbuf[2][BN * 128];
    __shared__ float rLo[BM], rHi[BM], cLo[BN], cHi[BN];
    __shared__ int rlab[BM], clab[BN];
    __shared__ uint32 tmpn[4][BM], tmps[4][BM];

    const int t = threadIdx.x;
    int tb = blockIdx.x;
    // triangular decode: tb -> (by, bx), by <= bx
    int by = (int)((2 * NB + 1 - sqrtf((float)((2 * NB + 1) * (2 * NB + 1)) -
                                       8.0f * (float)tb)) * 0.5f);
    if (by < 0) by = 0;
    if (by > NB - 1) by = NB - 1;
    while (by > 0 && (by * NB - by * (by - 1) / 2) > tb) --by;
    while (((by + 1) * NB - (by + 1) * by / 2) <= tb) ++by;
    const int bx = by + (tb - (by * NB - by * (by - 1) / 2));
    const int r0 = by * BM, c0 = bx * BN;

    const int w = t >> 6, lane = t & 63;
    const int wr = w >> 2, wc = w & 3;   // 2x4 wave grid; 64x32 per wave

    if (t < BM) {
        rlab[t] = labels[r0 + t];
        float dp = dpos[r0 + t];
        float dp2 = dp * dp;
        float dphi = dp + MARGIN;
        rHi[t] = (2.0f - dp2) * 0.5f;            // acc < aHi <=> sqd > dp2
        rLo[t] = (2.0f - dphi * dphi) * 0.5f;    // acc > aLo <=> sqd < dphi2
    } else if (t < 256) {
        int u = t - BM;
        clab[u] = labels[c0 + u];
        float dp = dpos[c0 + u];
        float dp2 = dp * dp;
        float dphi = dp + MARGIN;
        cHi[u] = (2.0f - dp2) * 0.5f;
        cLo[u] = (2.0f - dphi * dphi) * 0.5f;
    }

    f32x4 acc[4][2] = {};    // [m][n]
    f32x4 accT[2][4] = {};   // [n][m]

    // hoisted staging addresses: wave w stages chunks {w, w+8} per buffer.
    const int srow = lane >> 3;
    const int scol = ((lane & 7) ^ srow) << 3;   // fp16-elem offset
    const _Float16* gA0 = hp + (size_t)(r0 + srow) * D + scol + (size_t)w * 8 * D;
    const _Float16* gB0 = hp + (size_t)(c0 + srow) * D + scol + (size_t)w * 8 * D;
    const int ldso = w * 1024 + lane * 16;

#define STAGE(bufA, bufB, k0e)                                                  \
    {                                                                           \
        _Pragma("unroll")                                                       \
        for (int q = 0; q < 2; ++q) {                                           \
            const _Float16* gpa = gA0 + q * (8 * 8 * D) + (k0e);                \
            const _Float16* gpb = gB0 + q * (8 * 8 * D) + (k0e);                \
            char* lpa = (bufA) + q * 8192 + ldso;                               \
            char* lpb = (bufB) + q * 8192 + ldso;                               \
            __builtin_amdgcn_global_load_lds(                                   \
                (__attribute__((address_space(1))) void*)(void*)gpa,            \
                (__attribute__((address_space(3))) void*)lpa, 16, 0, 0);        \
            __builtin_amdgcn_global_load_lds(                                   \
                (__attribute__((address_space(1))) void*)(void*)gpb,            \
                (__attribute__((address_space(3))) void*)lpb, 16, 0, 0);        \
        }                                                                       \
    }

    STAGE(Abuf[0], Bbuf[0], 0);
    asm volatile("s_waitcnt vmcnt(0)" ::: "memory");
    __syncthreads();

    const int g2 = lane >> 4;
    const int lr = lane & 15;
    const int rsw = lr & 7;

#pragma unroll 1
    for (int s = 0; s < NCH; ++s) {
        const int cur = s & 1;
        if (s < NCH - 1) STAGE(Abuf[cur ^ 1], Bbuf[cur ^ 1], (s + 1) * 64);

#pragma unroll
        for (int kk = 0; kk < 2; ++kk) {
            const int cb = kk * 64 + (g2 << 4);
            half8 aF[4], bF[2];
#pragma unroll
            for (int m = 0; m < 4; ++m) {
                int ra = wr * 64 + m * 16 + lr;
                aF[m] = *reinterpret_cast<const half8*>(
                    Abuf[cur] + ra * 128 + (cb ^ (rsw << 4)));
            }
#pragma unroll
            for (int n = 0; n < 2; ++n) {
                int rb = wc * 32 + n * 16 + lr;
                bF[n] = *reinterpret_cast<const half8*>(
                    Bbuf[cur] + rb * 128 + (cb ^ (rsw << 4)));
            }
#pragma unroll
            for (int m = 0; m < 4; ++m)
#pragma unroll
                for (int n = 0; n < 2; ++n)
                    acc[m][n] = __builtin_amdgcn_mfma_f32_16x16x32_f16(
                        aF[m], bF[n], acc[m][n], 0, 0, 0);
#pragma unroll
            for (int n = 0; n < 2; ++n)
#pragma unroll
                for (int m = 0; m < 4; ++m)
                    accT[n][m] = __builtin_amdgcn_mfma_f32_16x16x32_f16(
                        bF[n], aF[m], accT[n][m], 0, 0, 0);
        }
        __syncthreads();
    }
#undef STAGE

    // ---- epilogue: all labels/thresholds/indices hoisted to registers ----
    // row pass constants
    int rowm[4]; int rlm[4]; float rLom[4], rHim[4];
#pragma unroll
    for (int m = 0; m < 4; ++m) {
        rowm[m] = wr * 64 + m * 16 + lr;
        rlm[m] = rlab[rowm[m]];
        rLom[m] = rLo[rowm[m]];
        rHim[m] = rHi[rowm[m]];
    }
    int4 clA = *reinterpret_cast<const int4*>(&clab[wc * 32 + g2 * 4]);
    int4 clB = *reinterpret_cast<const int4*>(&clab[wc * 32 + 16 + g2 * 4]);
    const int clv[8] = {clA.x, clA.y, clA.z, clA.w, clB.x, clB.y, clB.z, clB.w};
    // col pass constants
    int coln[2]; int cln[2]; float cLon[2], cHin[2];
#pragma unroll
    for (int n = 0; n < 2; ++n) {
        coln[n] = wc * 32 + n * 16 + lr;
        cln[n] = clab[coln[n]];
        cLon[n] = cLo[coln[n]];
        cHin[n] = cHi[coln[n]];
    }
    int rlq[16];
#pragma unroll
    for (int m = 0; m < 4; ++m) {
        int4 rv = *reinterpret_cast<const int4*>(&rlab[wr * 64 + m * 16 + g2 * 4]);
        rlq[m * 4 + 0] = rv.x; rlq[m * 4 + 1] = rv.y;
        rlq[m * 4 + 2] = rv.z; rlq[m * 4 + 3] = rv.w;
    }

    // row pass via accT: anchor row on lane dim, cols in-lane
#pragma unroll
    for (int m = 0; m < 4; ++m) {
        const int rl = rlm[m];
        const float aLo = rLom[m], aHi = rHim[m];
        uint32 kn = KINIT, ks = KINIT;
#pragma unroll
        for (int n = 0; n < 2; ++n)
#pragma unroll
            for (int reg = 0; reg < 4; ++reg) {
                float a = accT[n][m][reg];
                uint32 cidx = (uint32)(c0 + wc * 32 + n * 16 + g2 * 4 + reg);
                float qf = fmaf(a, -262144.0f, 262144.0f);
                qf = fminf(fmaxf(qf, 0.0f), QMAXF);
                uint32 key = ((uint32)qf << 13) | cidx;
                bool neq = (rl != clv[n * 4 + reg]);
                kn = minu(kn, neq ? key : KINIT);
                bool semi = neq && (a > aLo) && (a < aHi);
                ks = minu(ks, semi ? key : KINIT);
            }
        kn = minu(kn, (uint32)__shfl_xor((int)kn, 16, 64));
        kn = minu(kn, (uint32)__shfl_xor((int)kn, 32, 64));
        ks = minu(ks, (uint32)__shfl_xor((int)ks, 16, 64));
        ks = minu(ks, (uint32)__shfl_xor((int)ks, 32, 64));
        if (g2 == 0) {
            tmpn[wc][rowm[m]] = kn;
            tmps[wc][rowm[m]] = ks;
        }
    }
    __syncthreads();
    if (t < BM) {
        uint32 a0 = minu(tmpn[0][t], tmpn[1][t]);
        uint32 a1 = minu(tmpn[2][t], tmpn[3][t]);
        pr_n[(size_t)tb * BM + t] = minu(a0, a1);
        uint32 b0 = minu(tmps[0][t], tmps[1][t]);
        uint32 b1 = minu(tmps[2][t], tmps[3][t]);
        pr_s[(size_t)tb * BM + t] = minu(b0, b1);
    }
    __syncthreads();

    // col pass via acc: anchor col on lane dim, rows in-lane
#pragma unroll
    for (int n = 0; n < 2; ++n) {
        const int cl = cln[n];
        const float aLo = cLon[n], aHi = cHin[n];
        uint32 kn = KINIT, ks = KINIT;
#pragma unroll
        for (int m = 0; m < 4; ++m)
#pragma unroll
            for (int reg = 0; reg < 4; ++reg) {
                float a = acc[m][n][reg];
                uint32 ridx = (uint32)(r0 + wr * 64 + m * 16 + g2 * 4 + reg);
                float qf = fmaf(a, -262144.0f, 262144.0f);
                qf = fminf(fmaxf(qf, 0.0f), QMAXF);
                uint32 key = ((uint32)qf << 13) | ridx;
                bool neq = (cl != rlq[m * 4 + reg]);
                kn = minu(kn, neq ? key : KINIT);
                bool semi = neq && (a > aLo) && (a < aHi);
                ks = minu(ks, semi ? key : KINIT);
            }
        kn = minu(kn, (uint32)__shfl_xor((int)kn, 16, 64));
        kn = minu(kn, (uint32)__shfl_xor((int)kn, 32, 64));
        ks = minu(ks, (uint32)__shfl_xor((int)ks, 16, 64));
        ks = minu(ks, (uint32)__shfl_xor((int)ks, 32, 64));
        if (lane < 16) {
            tmpn[wr][coln[n]] = kn;
            tmps[wr][coln[n]] = ks;
        }
    }
    __syncthreads();
    if (t < BN) {
        pc_n[(size_t)tb * BN + t] = minu(tmpn[0][t], tmpn[1][t]);
        pc_s[(size_t)tb * BN + t] = minu(tmps[0][t], tmps[1][t]);
    }
}

// ---------------------------------------------------------------------------
// k_exact: one wave per anchor (16 waves/block). Lanes split the per-tile
// partials, shuffle-min, recompute selected pair exactly in f32. Finish:
// per-block deterministic integer pack (l_q<<16 | valid) -> one u64
// atomicAdd; counter-based last-block writes out. No k_final launch.
// ---------------------------------------------------------------------------
__global__ __launch_bounds__(1024) void k_exact(const float* __restrict__ x,
                                                const float* __restrict__ sq,
                                                const float* __restrict__ dpos,
                                                const uint32* __restrict__ pr_n,
                                                const uint32* __restrict__ pr_s,
                                                const uint32* __restrict__ pc_n,
                                                const uint32* __restrict__ pc_s,
                                                u64* __restrict__ acc_pack,
                                                unsigned* __restrict__ counter,
                                                float* __restrict__ out) {
    __shared__ float lsh[16], vsh[16];
    int wv = threadIdx.x >> 6;
    int lane = threadIdx.x & 63;
    const int i = blockIdx.x * 16 + wv;
    const int q = i >> 7, r = i & 127;

    const int Lr = NB - q;
    const int base = q * NB - q * (q - 1) / 2;
    uint32 kn = KINIT, ks = KINIT;

    for (int u = lane; u < Lr + q + 1; u += 64) {
        size_t off;
        if (u < Lr) {
            off = (size_t)(base + u) * BM + r;
            kn = minu(kn, pr_n[off]);
            ks = minu(ks, pr_s[off]);
        } else {
            int byy = u - Lr;           // 0..q
            int tb2 = byy * NB - byy * (byy - 1) / 2 + (q - byy);
            off = (size_t)tb2 * BN + r;
            kn = minu(kn, pc_n[off]);
            ks = minu(ks, pc_s[off]);
        }
    }
    for (int msk = 1; msk <= 32; msk <<= 1) {
        kn = minu(kn, (uint32)__shfl_xor((int)kn, msk, 64));
        ks = minu(ks, (uint32)__shfl_xor((int)ks, msk, 64));
    }

    bool has_neg = kn != KINIT;
    bool has_semi = ks != KINIT;
    float dp = dpos[i];
    bool has_pos = dp >= 0.0f;

    float l = 0.0f, v = 0.0f;
    if (has_pos && has_neg) {
        int j = (int)((has_semi ? ks : kn) & IDXMASK);
        float4 xi = reinterpret_cast<const float4*>(x + (size_t)i * D)[lane];
        float4 xj = reinterpret_cast<const float4*>(x + (size_t)j * D)[lane];
        float dotp = xi.x * xj.x + xi.y * xj.y + xi.z * xj.z + xi.w * xj.w;
        for (int m = 32; m >= 1; m >>= 1) dotp += __shfl_xor(dotp, m, 64);
        float sqd = fmaxf(sq[i] + sq[j] - 2.0f * dotp, 0.0f);
        float dn = sqd > 0.0f ? sqrtf(sqd) : 0.0f;
        l = fmaxf(dp - dn + MARGIN, 0.0f);
        v = 1.0f;
    }
    if (lane == 0) {
        lsh[wv] = l;
        vsh[wv] = v;
    }
    __syncthreads();
    if (threadIdx.x == 0) {
        u64 pack = 0;
#pragma unroll
        for (int k = 0; k < 16; ++k) {
            u64 lq = (u64)(lsh[k] * 1073741824.0f + 0.5f);   // 2^30 fixed-point
            pack += (lq << 16) | (u64)(vsh[k] != 0.0f ? 1u : 0u);
        }
        atomicAdd(acc_pack, pack);
        __threadfence();
        unsigned old = atomicAdd(counter, 1u);
        if (old == gridDim.x - 1) {
            u64 val = atomicAdd(acc_pack, (u64)0);
            double s = (double)(val >> 16) * (1.0 / 1073741824.0);
            double c = (double)(val & 0xFFFFull);
            out[0] = (float)(s / c);
        }
    }
}

// ---------------------------------------------------------------------------
extern "C" void kernel_launch(void* const* d_in, const int* in_sizes, int n_in,
                              void* d_out, int out_size, void* d_ws, size_t ws_size,
                              hipStream_t stream) {
    const float* x = (const float*)d_in[0];
    const int* labels = (const int*)d_in[1];
    float* out = (float*)d_out;

    // ws layout:
    // zero-zone: acc_pack u64 | counter u32 | pad u32 | cnt[512]  (2064 B)
    // sq[N] | dpos[N] | bkt[512*64] | hp[N*D] fp16 | pr_n | pr_s | pc_n | pc_s
    u64* acc_pack = (u64*)d_ws;
    unsigned* counter = (unsigned*)(acc_pack + 1);
    int* cnt = (int*)(counter + 2);                 // 8B-aligned zone
    float* sq = (float*)(cnt + 512);
    float* dpos = sq + N;
    int* bkt = (int*)(dpos + N);
    _Float16* hp = (_Float16*)(bkt + 512 * BCAP);
    uint32* pr_n = (uint32*)(hp + (size_t)N * D);
    uint32* pr_s = pr_n + (size_t)NTRI * BM;
    uint32* pc_n = pr_s + (size_t)NTRI * BM;
    uint32* pc_s = pc_n + (size_t)NTRI * BM;

    hipMemsetAsync(d_ws, 0, 2064, stream);   // acc_pack + counter + cnt
    hipLaunchKernelGGL(k_conv, dim3(N * D / 4 / 256), dim3(256), 0, stream,
                       x, labels, hp, cnt, bkt);
    hipLaunchKernelGGL(k_dpos, dim3(N / 4), dim3(256), 0, stream,
                       x, labels, cnt, bkt, sq, dpos);
    hipLaunchKernelGGL(k_main, dim3(NTRI), dim3(512), 0, stream,
                       hp, labels, dpos, pr_n, pr_s, pc_n, pc_s);
    hipLaunchKernelGGL(k_exact, dim3(N / 16), dim3(1024), 0, stream,
                       x, sq, dpos, pr_n, pr_s, pc_n, pc_s,
                       acc_pack, counter, out);
}

// Round 13
// 118.428 us; speedup vs baseline: 1.0634x; 1.0634x over previous
//
#include <hip/hip_runtime.h>
#include <hip/hip_bf16.h>
#include <math.h>

#define N 8192
#define D 256
#define MARGIN 1.0f

#define BM 128
#define BN 128
#define NCH 4            // K-chunks of 64 fp16 elems (128B per row)
#define NB (N / BM)      // 64
#define NTRI (NB * (NB + 1) / 2)   // 2080
#define BCAP 64          // class bucket capacity

#define KINIT 0xFFFFFFFFu
#define IDXMASK 0x1FFFu          // 13 bits (N=8192)

typedef __attribute__((ext_vector_type(8))) _Float16 half8;
typedef __attribute__((ext_vector_type(4))) _Float16 half4;
typedef __attribute__((ext_vector_type(4))) float f32x4;
typedef unsigned int uint32;
typedef unsigned long long u64;

__device__ __forceinline__ uint32 minu(uint32 a, uint32 b) { return a < b ? a : b; }

// key: rounded float-bit quantization of fsq (>=0), monotone, 19 value bits
// + 13 index bits. Rounding (not truncation) -> no systematic d_neg bias.
__device__ __forceinline__ uint32 mkkey(float fsq, uint32 idx) {
    uint32 u = __float_as_uint(fsq);
    return ((u + 0x1000u) & 0xFFFFE000u) | idx;
}

// ---------------------------------------------------------------------------
// k_conv: f32 -> fp16 plane + class buckets.
// ---------------------------------------------------------------------------
__global__ __launch_bounds__(256) void k_conv(const float* __restrict__ x,
                                              const int* __restrict__ labels,
                                              _Float16* __restrict__ hp,
                                              int* __restrict__ cnt,
                                              int* __restrict__ bkt) {
    int i = blockIdx.x * 256 + threadIdx.x;
    float4 v = reinterpret_cast<const float4*>(x)[i];
    half4 h;
    h[0] = (_Float16)v.x; h[1] = (_Float16)v.y;
    h[2] = (_Float16)v.z; h[3] = (_Float16)v.w;
    reinterpret_cast<half4*>(hp)[i] = h;
    if (i < N) {
        int lb = labels[i];
        int p = atomicAdd(&cnt[lb], 1);
        if (p < BCAP) bkt[lb * BCAP + p] = i;
    }
}

// ---------------------------------------------------------------------------
// k_dpos: one wave per anchor; exact f32 d_pos via class buckets.
// ---------------------------------------------------------------------------
__global__ __launch_bounds__(256) void k_dpos(const float* __restrict__ x,
                                              const int* __restrict__ labels,
                                              const int* __restrict__ cnt,
                                              const int* __restrict__ bkt,
                                              float* __restrict__ dpos) {
    int wave = (blockIdx.x * blockDim.x + threadIdx.x) >> 6;
    int lane = threadIdx.x & 63;
    if (wave >= N) return;
    const int i = wave;

    float4 xi = reinterpret_cast<const float4*>(x + (size_t)i * D)[lane];
    float sqi = xi.x * xi.x + xi.y * xi.y + xi.z * xi.z + xi.w * xi.w;
    for (int m = 32; m >= 1; m >>= 1) sqi += __shfl_xor(sqi, m, 64);

    const int L = labels[i];
    int c = cnt[L]; if (c > BCAP) c = BCAP;
    float dp = -1.0f;

    for (int e = 0; e < c; ++e) {
        int j = bkt[L * BCAP + e];
        if (j == i) continue;
        float4 xj = reinterpret_cast<const float4*>(x + (size_t)j * D)[lane];
        float dotp = xi.x * xj.x + xi.y * xj.y + xi.z * xj.z + xi.w * xj.w;
        float sqjp = xj.x * xj.x + xj.y * xj.y + xj.z * xj.z + xj.w * xj.w;
        for (int m = 32; m >= 1; m >>= 1) {
            dotp += __shfl_xor(dotp, m, 64);
            sqjp += __shfl_xor(sqjp, m, 64);
        }
        float sqd = fmaxf(sqi + sqjp - 2.0f * dotp, 0.0f);
        float dist = sqd > 0.0f ? sqrtf(sqd) : 0.0f;
        dp = fmaxf(dp, dist);
    }

    if (lane == 0) dpos[i] = dp;
}

// ---------------------------------------------------------------------------
// k_main: symmetric fp16 MFMA GEMM, 8 waves (2x4), 64x32/wave, acc + accT.
// r13: float-bit keys (mkkey) replace fixed-point quantization; everything
// else is the r11/r12-proven core (0-conflict swizzle, dbuf, plain partial
// stores, no global atomics).
// ---------------------------------------------------------------------------
__global__ __launch_bounds__(512) void k_main(const _Float16* __restrict__ hp,
                                              const int* __restrict__ labels,
                                              const float* __restrict__ dpos,
                                              uint32* __restrict__ pr_n,
                                              uint32* __restrict__ pr_s,
                                              uint32* __restrict__ pc_n,
                                              uint32* __restrict__ pc_s) {
    __shared__ char Abuf[2][BM * 128];   // 16 KB each
    __shared__ char Bbuf[2][BN * 128];
    __shared__ float rLo[BM], rHi[BM], cLo[BN], cHi[BN];
    __shared__ int rlab[BM], clab[BN];
    __shared__ uint32 tmpn[4][BM], tmps[4][BM];

    const int t = threadIdx.x;
    int tb = blockIdx.x;
    // triangular decode: tb -> (by, bx), by <= bx
    int by = (int)((2 * NB + 1 - sqrtf((float)((2 * NB + 1) * (2 * NB + 1)) -
                                       8.0f * (float)tb)) * 0.5f);
    if (by < 0) by = 0;
    if (by > NB - 1) by = NB - 1;
    while (by > 0 && (by * NB - by * (by - 1) / 2) > tb) --by;
    while (((by + 1) * NB - (by + 1) * by / 2) <= tb) ++by;
    const int bx = by + (tb - (by * NB - by * (by - 1) / 2));
    const int r0 = by * BM, c0 = bx * BN;

    const int w = t >> 6, lane = t & 63;
    const int wr = w >> 2, wc = w & 3;   // 2x4 wave grid; 64x32 per wave

    if (t < BM) {
        rlab[t] = labels[r0 + t];
        float dp = dpos[r0 + t];
        float dp2 = dp * dp;
        float dphi = dp + MARGIN;
        rHi[t] = (2.0f - dp2) * 0.5f;            // acc < aHi <=> sqd > dp2
        rLo[t] = (2.0f - dphi * dphi) * 0.5f;    // acc > aLo <=> sqd < dphi2
    } else if (t < 256) {
        int u = t - BM;
        clab[u] = labels[c0 + u];
        float dp = dpos[c0 + u];
        float dp2 = dp * dp;
        float dphi = dp + MARGIN;
        cHi[u] = (2.0f - dp2) * 0.5f;
        cLo[u] = (2.0f - dphi * dphi) * 0.5f;
    }

    f32x4 acc[4][2] = {};    // [m][n]
    f32x4 accT[2][4] = {};   // [n][m]

    // hoisted staging addresses: wave w stages chunks {w, w+8} per buffer.
    const int srow = lane >> 3;
    const int scol = ((lane & 7) ^ srow) << 3;   // fp16-elem offset
    const _Float16* gA0 = hp + (size_t)(r0 + srow) * D + scol + (size_t)w * 8 * D;
    const _Float16* gB0 = hp + (size_t)(c0 + srow) * D + scol + (size_t)w * 8 * D;
    const int ldso = w * 1024 + lane * 16;

#define STAGE(bufA, bufB, k0e)                                                  \
    {                                                                           \
        _Pragma("unroll")                                                       \
        for (int q = 0; q < 2; ++q) {                                           \
            const _Float16* gpa = gA0 + q * (8 * 8 * D) + (k0e);                \
            const _Float16* gpb = gB0 + q * (8 * 8 * D) + (k0e);                \
            char* lpa = (bufA) + q * 8192 + ldso;                               \
            char* lpb = (bufB) + q * 8192 + ldso;                               \
            __builtin_amdgcn_global_load_lds(                                   \
                (__attribute__((address_space(1))) void*)(void*)gpa,            \
                (__attribute__((address_space(3))) void*)lpa, 16, 0, 0);        \
            __builtin_amdgcn_global_load_lds(                                   \
                (__attribute__((address_space(1))) void*)(void*)gpb,            \
                (__attribute__((address_space(3))) void*)lpb, 16, 0, 0);        \
        }                                                                       \
    }

    STAGE(Abuf[0], Bbuf[0], 0);
    asm volatile("s_waitcnt vmcnt(0)" ::: "memory");
    __syncthreads();

    const int g2 = lane >> 4;
    const int lr = lane & 15;
    const int rsw = lr & 7;

#pragma unroll 1
    for (int s = 0; s < NCH; ++s) {
        const int cur = s & 1;
        if (s < NCH - 1) STAGE(Abuf[cur ^ 1], Bbuf[cur ^ 1], (s + 1) * 64);

#pragma unroll
        for (int kk = 0; kk < 2; ++kk) {
            const int cb = kk * 64 + (g2 << 4);
            half8 aF[4], bF[2];
#pragma unroll
            for (int m = 0; m < 4; ++m) {
                int ra = wr * 64 + m * 16 + lr;
                aF[m] = *reinterpret_cast<const half8*>(
                    Abuf[cur] + ra * 128 + (cb ^ (rsw << 4)));
            }
#pragma unroll
            for (int n = 0; n < 2; ++n) {
                int rb = wc * 32 + n * 16 + lr;
                bF[n] = *reinterpret_cast<const half8*>(
                    Bbuf[cur] + rb * 128 + (cb ^ (rsw << 4)));
            }
#pragma unroll
            for (int m = 0; m < 4; ++m)
#pragma unroll
                for (int n = 0; n < 2; ++n)
                    acc[m][n] = __builtin_amdgcn_mfma_f32_16x16x32_f16(
                        aF[m], bF[n], acc[m][n], 0, 0, 0);
#pragma unroll
            for (int n = 0; n < 2; ++n)
#pragma unroll
                for (int m = 0; m < 4; ++m)
                    accT[n][m] = __builtin_amdgcn_mfma_f32_16x16x32_f16(
                        bF[n], aF[m], accT[n][m], 0, 0, 0);
        }
        __syncthreads();
    }
#undef STAGE

    // ---- epilogue: unit-norm fsq = 2-2a, float-bit keys, no atomics ----
    int rowm[4]; int rlm[4]; float rLom[4], rHim[4];
#pragma unroll
    for (int m = 0; m < 4; ++m) {
        rowm[m] = wr * 64 + m * 16 + lr;
        rlm[m] = rlab[rowm[m]];
        rLom[m] = rLo[rowm[m]];
        rHim[m] = rHi[rowm[m]];
    }
    int4 clA = *reinterpret_cast<const int4*>(&clab[wc * 32 + g2 * 4]);
    int4 clB = *reinterpret_cast<const int4*>(&clab[wc * 32 + 16 + g2 * 4]);
    const int clv[8] = {clA.x, clA.y, clA.z, clA.w, clB.x, clB.y, clB.z, clB.w};
    int coln[2]; int cln[2]; float cLon[2], cHin[2];
#pragma unroll
    for (int n = 0; n < 2; ++n) {
        coln[n] = wc * 32 + n * 16 + lr;
        cln[n] = clab[coln[n]];
        cLon[n] = cLo[coln[n]];
        cHin[n] = cHi[coln[n]];
    }
    int rlq[16];
#pragma unroll
    for (int m = 0; m < 4; ++m) {
        int4 rv = *reinterpret_cast<const int4*>(&rlab[wr * 64 + m * 16 + g2 * 4]);
        rlq[m * 4 + 0] = rv.x; rlq[m * 4 + 1] = rv.y;
        rlq[m * 4 + 2] = rv.z; rlq[m * 4 + 3] = rv.w;
    }

    // row pass via accT: anchor row on lane dim, cols in-lane
#pragma unroll
    for (int m = 0; m < 4; ++m) {
        const int rl = rlm[m];
        const float aLo = rLom[m], aHi = rHim[m];
        uint32 kn = KINIT, ks = KINIT;
#pragma unroll
        for (int n = 0; n < 2; ++n)
#pragma unroll
            for (int reg = 0; reg < 4; ++reg) {
                float a = accT[n][m][reg];
                float fsq = fmaxf(fmaf(-2.0f, a, 2.0f), 0.0f);
                uint32 key = mkkey(fsq, (uint32)(c0 + wc * 32 + n * 16 + g2 * 4 + reg));
                bool neq = (rl != clv[n * 4 + reg]);
                kn = minu(kn, neq ? key : KINIT);
                bool semi = neq && (a > aLo) && (a < aHi);
                ks = minu(ks, semi ? key : KINIT);
            }
        kn = minu(kn, (uint32)__shfl_xor((int)kn, 16, 64));
        kn = minu(kn, (uint32)__shfl_xor((int)kn, 32, 64));
        ks = minu(ks, (uint32)__shfl_xor((int)ks, 16, 64));
        ks = minu(ks, (uint32)__shfl_xor((int)ks, 32, 64));
        if (g2 == 0) {
            tmpn[wc][rowm[m]] = kn;
            tmps[wc][rowm[m]] = ks;
        }
    }
    __syncthreads();
    if (t < BM) {
        uint32 a0 = minu(tmpn[0][t], tmpn[1][t]);
        uint32 a1 = minu(tmpn[2][t], tmpn[3][t]);
        pr_n[(size_t)tb * BM + t] = minu(a0, a1);
        uint32 b0 = minu(tmps[0][t], tmps[1][t]);
        uint32 b1 = minu(tmps[2][t], tmps[3][t]);
        pr_s[(size_t)tb * BM + t] = minu(b0, b1);
    }
    __syncthreads();

    // col pass via acc: anchor col on lane dim, rows in-lane
#pragma unroll
    for (int n = 0; n < 2; ++n) {
        const int cl = cln[n];
        const float aLo = cLon[n], aHi = cHin[n];
        uint32 kn = KINIT, ks = KINIT;
#pragma unroll
        for (int m = 0; m < 4; ++m)
#pragma unroll
            for (int reg = 0; reg < 4; ++reg) {
                float a = acc[m][n][reg];
                float fsq = fmaxf(fmaf(-2.0f, a, 2.0f), 0.0f);
                uint32 key = mkkey(fsq, (uint32)(r0 + wr * 64 + m * 16 + g2 * 4 + reg));
                bool neq = (cl != rlq[m * 4 + reg]);
                kn = minu(kn, neq ? key : KINIT);
                bool semi = neq && (a > aLo) && (a < aHi);
                ks = minu(ks, semi ? key : KINIT);
            }
        kn = minu(kn, (uint32)__shfl_xor((int)kn, 16, 64));
        kn = minu(kn, (uint32)__shfl_xor((int)kn, 32, 64));
        ks = minu(ks, (uint32)__shfl_xor((int)ks, 16, 64));
        ks = minu(ks, (uint32)__shfl_xor((int)ks, 32, 64));
        if (lane < 16) {
            tmpn[wr][coln[n]] = kn;
            tmps[wr][coln[n]] = ks;
        }
    }
    __syncthreads();
    if (t < BN) {
        pc_n[(size_t)tb * BN + t] = minu(tmpn[0][t], tmpn[1][t]);
        pc_s[(size_t)tb * BN + t] = minu(tmps[0][t], tmps[1][t]);
    }
}

// ---------------------------------------------------------------------------
// k_finish: 64 blocks, one per anchor block-row q. Folds all per-tile
// partials with COALESCED loads (threads sweep each tile's contiguous
// 128-word row; 2-way tile split + LDS combine), computes per-anchor loss
// directly from the dequantized float-bit key (no exact recompute; error
// ~2e-4/anchor, random sign), then one deterministic packed-integer
// atomicAdd per block; last block writes the mean.
// ---------------------------------------------------------------------------
__global__ __launch_bounds__(256) void k_finish(const float* __restrict__ dpos,
                                                const uint32* __restrict__ pr_n,
                                                const uint32* __restrict__ pr_s,
                                                const uint32* __restrict__ pc_n,
                                                const uint32* __restrict__ pc_s,
                                                u64* __restrict__ acc_pack,
                                                unsigned* __restrict__ counter,
                                                float* __restrict__ out) {
    __shared__ uint32 shn[2][128], shs[2][128];
    __shared__ u64 wpart[2];
    const int q = blockIdx.x;
    const int t = threadIdx.x;
    const int half = t >> 7, a = t & 127;
    const int Lr = NB - q;
    const int base = q * NB - q * (q - 1) / 2;
    const int ntiles = Lr + q + 1;   // row tiles + col tiles (diag in both)

    uint32 kn = KINIT, ks = KINIT;
    for (int u = half; u < ntiles; u += 2) {
        size_t off;
        const uint32 *Pn, *Ps;
        if (u < Lr) {
            off = (size_t)(base + u) * BM + a;
            Pn = pr_n; Ps = pr_s;
        } else {
            int byy = u - Lr;    // 0..q
            int tb2 = byy * NB - byy * (byy - 1) / 2 + (q - byy);
            off = (size_t)tb2 * BN + a;
            Pn = pc_n; Ps = pc_s;
        }
        kn = minu(kn, Pn[off]);
        ks = minu(ks, Ps[off]);
    }
    shn[half][a] = kn;
    shs[half][a] = ks;
    __syncthreads();

    u64 pack = 0;
    if (t < 128) {
        kn = minu(shn[0][t], shn[1][t]);
        ks = minu(shs[0][t], shs[1][t]);
        float dp = dpos[q * 128 + t];
        if (dp >= 0.0f && kn != KINIT) {
            uint32 key = (ks != KINIT) ? ks : kn;
            float fsq = __uint_as_float(key & 0xFFFFE000u);
            float dn = sqrtf(fsq);
            float l = fmaxf(dp - dn + MARGIN, 0.0f);
            u64 lq = (u64)(l * 1073741824.0f + 0.5f);   // 2^30 fixed-point
            pack = (lq << 16) | 1ull;
        }
    }
    for (int m = 1; m <= 32; m <<= 1) pack += __shfl_xor(pack, m, 64);
    if (t < 128 && (t & 63) == 0) wpart[t >> 6] = pack;
    __syncthreads();
    if (t == 0) {
        atomicAdd(acc_pack, wpart[0] + wpart[1]);
        __threadfence();
        unsigned old = atomicAdd(counter, 1u);
        if (old == gridDim.x - 1) {
            u64 val = atomicAdd(acc_pack, (u64)0);
            double s = (double)(val >> 16) * (1.0 / 1073741824.0);
            double c = (double)(val & 0xFFFFull);
            out[0] = (float)(s / c);
        }
    }
}

// ---------------------------------------------------------------------------
extern "C" void kernel_launch(void* const* d_in, const int* in_sizes, int n_in,
                              void* d_out, int out_size, void* d_ws, size_t ws_size,
                              hipStream_t stream) {
    const float* x = (const float*)d_in[0];
    const int* labels = (const int*)d_in[1];
    float* out = (float*)d_out;

    // ws layout:
    // zero-zone: acc_pack u64 | counter u32 | pad u32 | cnt[512]  (2064 B)
    // dpos[N] | bkt[512*64] | hp[N*D] fp16 | pr_n | pr_s | pc_n | pc_s
    u64* acc_pack = (u64*)d_ws;
    unsigned* counter = (unsigned*)(acc_pack + 1);
    int* cnt = (int*)(counter + 2);
    float* dpos = (float*)(cnt + 512);
    int* bkt = (int*)(dpos + N);
    _Float16* hp = (_Float16*)(bkt + 512 * BCAP);
    uint32* pr_n = (uint32*)(hp + (size_t)N * D);
    uint32* pr_s = pr_n + (size_t)NTRI * BM;
    uint32* pc_n = pr_s + (size_t)NTRI * BM;
    uint32* pc_s = pc_n + (size_t)NTRI * BM;

    hipMemsetAsync(d_ws, 0, 2064, stream);
    hipLaunchKernelGGL(k_conv, dim3(N * D / 4 / 256), dim3(256), 0, stream,
                       x, labels, hp, cnt, bkt);
    hipLaunchKernelGGL(k_dpos, dim3(N / 4), dim3(256), 0, stream,
                       x, labels, cnt, bkt, dpos);
    hipLaunchKernelGGL(k_main, dim3(NTRI), dim3(512), 0, stream,
                       hp, labels, dpos, pr_n, pr_s, pc_n, pc_s);
    hipLaunchKernelGGL(k_finish, dim3(NB), dim3(256), 0, stream,
                       dpos, pr_n, pr_s, pc_n, pc_s, acc_pack, counter, out);
}